// Round 8
// baseline (359.528 us; speedup 1.0000x reference)
//
#include <hip/hip_runtime.h>
#include <stdint.h>

typedef __bf16 bf16x8 __attribute__((ext_vector_type(8)));
typedef float f32x4 __attribute__((ext_vector_type(4)));
typedef unsigned short u16;

__device__ __forceinline__ u16 f2b(float f) {
  union { float f; uint32_t u; } a; a.f = f;
  return (u16)((a.u + 0x7FFFu + ((a.u >> 16) & 1u)) >> 16);  // RNE
}
__device__ __forceinline__ float b2f(u16 b) {
  union { uint32_t u; float f; } a; a.u = ((uint32_t)b) << 16; return a.f;
}
__device__ __forceinline__ float blo(uint32_t w) {
  union { uint32_t u; float f; } a; a.u = w << 16; return a.f;
}
__device__ __forceinline__ float bhi(uint32_t w) {
  union { uint32_t u; float f; } a; a.u = w & 0xFFFF0000u; return a.f;
}
__device__ __forceinline__ void gload16(const u16* g, u16* l) {
  __builtin_amdgcn_global_load_lds(
      (const __attribute__((address_space(1))) void*)g,
      (__attribute__((address_space(3))) void*)l, 16, 0, 0);
}

// ---------------- f32 -> bf16 convert (x input) ----------------
__global__ void cvt_kernel(const float* __restrict__ in, u16* __restrict__ out, int n4) {
  int i = blockIdx.x * 256 + threadIdx.x;
  if (i >= n4) return;
  float4 v = reinterpret_cast<const float4*>(in)[i];
  ushort4 o;
  o.x = f2b(v.x); o.y = f2b(v.y); o.z = f2b(v.z); o.w = f2b(v.w);
  reinterpret_cast<ushort4*>(out)[i] = o;
}

// ---------------- 4 weight tensors in one launch (256 blocks each) ----------------
__global__ void cvt4_kernel(const float* __restrict__ w0, const float* __restrict__ w1,
                            const float* __restrict__ w2, const float* __restrict__ w3,
                            u16* __restrict__ o0, u16* __restrict__ o1,
                            u16* __restrict__ o2, u16* __restrict__ o3) {
  int g = blockIdx.x >> 8;
  int i = (blockIdx.x & 255) * 256 + threadIdx.x;
  const float* in = (g == 0) ? w0 : (g == 1) ? w1 : (g == 2) ? w2 : w3;
  u16* out = (g == 0) ? o0 : (g == 1) ? o1 : (g == 2) ? o2 : o3;
  float4 v = reinterpret_cast<const float4*>(in)[i];
  ushort4 o;
  o.x = f2b(v.x); o.y = f2b(v.y); o.z = f2b(v.z); o.w = f2b(v.w);
  reinterpret_cast<ushort4*>(out)[i] = o;
}

// ---------------- bf16 MFMA GEMM (m97 pattern): C[m,n] = sum_k A[m,k]*Bt[n,k] ----------------
// 128x128 tile, BK=32, linear LDS [128][32], global_load_lds width-16 staging.
#define BM 128
#define BN 128
#define BKK 32

template<bool PROJ>
__global__ __launch_bounds__(256) void gemm_bt(
    const u16* __restrict__ A, const u16* __restrict__ Bt,
    u16* __restrict__ Cb, float* __restrict__ Cf, const float* __restrict__ bias,
    int N, int K)
{
  __shared__ __align__(16) u16 As[BM * BKK];   // 8 KB
  __shared__ __align__(16) u16 Bs[BN * BKK];   // 8 KB
  const int tid = threadIdx.x;
  const int lane = tid & 63;
  const int wid = tid >> 6;
  const int wm = wid >> 1, wn = wid & 1;
  const size_t bm = (size_t)blockIdx.y * BM;
  const size_t bn = (size_t)blockIdx.x * BN;

  f32x4 acc[4][4] = {};
  const int fr = lane & 15;
  const int fk = (lane >> 4) * 8;

  // staging: 16 segments of 1KB (16 rows each); wave w owns segs {w, w+4} for A and B.
  // within a seg: lane l -> row = seg*16 + l/4, 16B chunk c = l&3  (linear dest)
  const int rA0 = wid * 16 + (lane >> 2);
  const int rA1 = rA0 + 64;
  const int cc = (lane & 3) * 8;
  const u16* srcA0 = A + (bm + rA0) * (size_t)K + cc;
  const u16* srcA1 = A + (bm + rA1) * (size_t)K + cc;
  const u16* srcB0 = Bt + (bn + rA0) * (size_t)K + cc;
  const u16* srcB1 = Bt + (bn + rA1) * (size_t)K + cc;
  u16* dstA0 = &As[wid * 512];          // wave-uniform base; HW adds lane*16B
  u16* dstA1 = &As[(wid + 4) * 512];
  u16* dstB0 = &Bs[wid * 512];
  u16* dstB1 = &Bs[(wid + 4) * 512];

  for (int k0 = 0; k0 < K; k0 += BKK) {
    __syncthreads();                    // prev iter's frag reads done
    gload16(srcA0 + k0, dstA0);
    gload16(srcA1 + k0, dstA1);
    gload16(srcB0 + k0, dstB0);
    gload16(srcB1 + k0, dstB1);
    __syncthreads();                    // drains vmcnt -> LDS tile ready
    bf16x8 af[4], bv[4];
#pragma unroll
    for (int m = 0; m < 4; ++m)
      af[m] = *reinterpret_cast<const bf16x8*>(&As[(wm * 64 + m * 16 + fr) * BKK + fk]);
#pragma unroll
    for (int n = 0; n < 4; ++n)
      bv[n] = *reinterpret_cast<const bf16x8*>(&Bs[(wn * 64 + n * 16 + fr) * BKK + fk]);
#pragma unroll
    for (int m = 0; m < 4; ++m)
#pragma unroll
      for (int n = 0; n < 4; ++n)
        acc[m][n] = __builtin_amdgcn_mfma_f32_16x16x32_bf16(af[m], bv[n], acc[m][n], 0, 0, 0);
  }
  const int fq = lane >> 4;
#pragma unroll
  for (int m = 0; m < 4; ++m) {
#pragma unroll
    for (int n = 0; n < 4; ++n) {
#pragma unroll
      for (int r = 0; r < 4; ++r) {
        size_t row = bm + wm * 64 + m * 16 + fq * 4 + r;
        size_t col = bn + wn * 64 + n * 16 + fr;
        float v = acc[m][n][r];
        if (PROJ) Cf[row * N + col] = v + bias[col];
        else      Cb[row * N + col] = f2b(v);
      }
    }
  }
}

// ---------------- per-pixel attention: 2 waves per pixel, 2 pixels per block ----------------
// wave dhalf handles d in [32*dhalf, 32*dhalf+32); partials combined via LDS.
struct SliceU {
  union { float vh[8][68]; float k2s[64][12]; } u;  // 3072 B
  float vvs[64][12];                                // 3072 B
  float a8[64];                                     // 256 B
  float outp[64][8];                                // 2048 B (wave1 partial)
};                                                  // 8448 B / pixel

__global__ __launch_bounds__(256, 7) void attn_pixel(
    const u16* __restrict__ QKV, u16* __restrict__ Sc)
{
  __shared__ __align__(16) SliceU sl[2];            // 16896 B / block
  const int tid = threadIdx.x;
  const int wid = tid >> 6;
  const int lane = tid & 63;
  const int dhalf = wid & 1;
  SliceU& S = sl[wid >> 1];

  const int bid = blockIdx.x;                       // 8192 blocks
  const int pp = (bid & 7) * 1024 + (bid >> 3);     // XCD-chunked swizzle
  const int pix = pp * 2 + (wid >> 1);
  const int b = pix >> 12;
  const int n = pix & 4095;
  const u16* P = QKV + (size_t)pix * 1536;

  // --- norms (vector form), only the tensors this wave uses ---
  float nq, nx;   // nx = nk (wave1) or nv (wave0)
  {
    uint4 r = *reinterpret_cast<const uint4*>(P + lane * 8);
    float s = blo(r.x)*blo(r.x) + bhi(r.x)*bhi(r.x) + blo(r.y)*blo(r.y) + bhi(r.y)*bhi(r.y)
            + blo(r.z)*blo(r.z) + bhi(r.z)*bhi(r.z) + blo(r.w)*blo(r.w) + bhi(r.w)*bhi(r.w);
    s += __shfl_xor(s, 1, 64); s += __shfl_xor(s, 2, 64); s += __shfl_xor(s, 4, 64);
    nq = s;
  }
  {
    const u16* px = P + (dhalf ? 512 : 1024) + lane * 8;
    uint4 r = *reinterpret_cast<const uint4*>(px);
    float s = blo(r.x)*blo(r.x) + bhi(r.x)*bhi(r.x) + blo(r.y)*blo(r.y) + bhi(r.y)*bhi(r.y)
            + blo(r.z)*blo(r.z) + bhi(r.z)*bhi(r.z) + blo(r.w)*blo(r.w) + bhi(r.w)*bhi(r.w);
    s += __shfl_xor(s, 1, 64); s += __shfl_xor(s, 2, 64); s += __shfl_xor(s, 4, 64);
    nx = s;
  }

  // --- scalar loads (lane = dim) ---
  float qv[8], xv[8];    // xv = kv (wave1) or vv (wave0, doubled)
#pragma unroll
  for (int h = 0; h < 8; ++h) {
    qv[h] = b2f(P[h * 64 + lane]);
    xv[h] = dhalf ? b2f(P[512 + h * 64 + lane]) : 2.0f * b2f(P[1024 + h * 64 + lane]);
  }

  if (!dhalf) {
    // vvs (raw doubled v) + normalized vh
    *reinterpret_cast<float4*>(&S.vvs[lane][0]) = make_float4(xv[0], xv[1], xv[2], xv[3]);
    *reinterpret_cast<float4*>(&S.vvs[lane][4]) = make_float4(xv[4], xv[5], xv[6], xv[7]);
#pragma unroll
    for (int h = 0; h < 8; ++h) {
      float sv = __shfl(nx, h * 8, 64);
      S.u.vh[h][lane] = xv[h] * (1.0f / fmaxf(2.0f * sqrtf(sv), 1e-12f));
    }
  }
#pragma unroll
  for (int h = 0; h < 8; ++h) {
    float sq = __shfl(nq, h * 8, 64);
    qv[h] *= 1.0f / fmaxf(sqrtf(sq), 1e-12f);
    if (dhalf) {
      float sk = __shfl(nx, h * 8, 64);
      xv[h] *= 1.0f / fmaxf(sqrtf(sk), 1e-12f);
    }
  }
  __syncthreads();   // b1: vh, vvs ready

  if (!dhalf) {
    // 8x8 gram of v_h; lane -> (hh,gg); |G|<=1 -> exp without max-sub
    const int hh = lane >> 3, gg = lane & 7;
    float g = 0.0f;
#pragma unroll
    for (int i = 0; i < 64; i += 4) {
      float4 a = *reinterpret_cast<const float4*>(&S.u.vh[hh][i]);
      float4 c = *reinterpret_cast<const float4*>(&S.u.vh[gg][i]);
      g += a.x * c.x + a.y * c.y + a.z * c.z + a.w * c.w;
    }
    float ex = __expf(g);
    float sum = ex;
    sum += __shfl_xor(sum, 1, 64);
    sum += __shfl_xor(sum, 2, 64);
    sum += __shfl_xor(sum, 4, 64);
    S.a8[lane] = ex / sum;
  }
  __syncthreads();   // b2: a8 ready (also: all vh reads done)

  // head-mix (q for both waves; k only on wave1)
  float q2r[8];
#pragma unroll
  for (int h = 0; h < 8; ++h) {
    float4 a0 = *reinterpret_cast<const float4*>(&S.a8[h * 8]);
    float4 a1 = *reinterpret_cast<const float4*>(&S.a8[h * 8 + 4]);
    q2r[h] = a0.x * qv[0] + a0.y * qv[1] + a0.z * qv[2] + a0.w * qv[3]
           + a1.x * qv[4] + a1.y * qv[5] + a1.z * qv[6] + a1.w * qv[7];
  }
  if (dhalf) {
    float k2r[8];
#pragma unroll
    for (int h = 0; h < 8; ++h) {
      float4 a0 = *reinterpret_cast<const float4*>(&S.a8[h * 8]);
      float4 a1 = *reinterpret_cast<const float4*>(&S.a8[h * 8 + 4]);
      k2r[h] = a0.x * xv[0] + a0.y * xv[1] + a0.z * xv[2] + a0.w * xv[3]
             + a1.x * xv[4] + a1.y * xv[5] + a1.z * xv[6] + a1.w * xv[7];
    }
    // k2 transposed into LDS (overlays vh; vh reads all finished at b2)
    *reinterpret_cast<float4*>(&S.u.k2s[lane][0]) = make_float4(k2r[0], k2r[1], k2r[2], k2r[3]);
    *reinterpret_cast<float4*>(&S.u.k2s[lane][4]) = make_float4(k2r[4], k2r[5], k2r[6], k2r[7]);
  }
  __syncthreads();   // b3: k2s ready

  // --- stage 2, lane = e, this wave's 32 d's; |S|<=8 -> no max-sub ---
  float out[8] = {0, 0, 0, 0, 0, 0, 0, 0};
  const int dbase = dhalf * 32;
#pragma unroll
  for (int d0 = 0; d0 < 32; d0 += 4) {
    float p[4];
#pragma unroll
    for (int j = 0; j < 4; ++j) {
      const int d = dbase + d0 + j;
      float4 ka = *reinterpret_cast<const float4*>(&S.u.k2s[d][0]);
      float4 kb = *reinterpret_cast<const float4*>(&S.u.k2s[d][4]);
      float s = ka.x * q2r[0] + ka.y * q2r[1] + ka.z * q2r[2] + ka.w * q2r[3]
              + kb.x * q2r[4] + kb.y * q2r[5] + kb.z * q2r[6] + kb.w * q2r[7];
      p[j] = __expf(s);
    }
#pragma unroll
    for (int j = 0; j < 4; ++j) {
      const int d = dbase + d0 + j;
      float t = p[j];
      t += __shfl_xor(t, 1, 64);
      t += __shfl_xor(t, 2, 64);
      t += __shfl_xor(t, 4, 64);
      t += __shfl_xor(t, 8, 64);
      t += __shfl_xor(t, 16, 64);
      t += __shfl_xor(t, 32, 64);
      float ip = p[j] * __builtin_amdgcn_rcpf(t);
      float4 va = *reinterpret_cast<const float4*>(&S.vvs[d][0]);
      float4 vb = *reinterpret_cast<const float4*>(&S.vvs[d][4]);
      out[0] += va.x * ip; out[1] += va.y * ip; out[2] += va.z * ip; out[3] += va.w * ip;
      out[4] += vb.x * ip; out[5] += vb.y * ip; out[6] += vb.z * ip; out[7] += vb.w * ip;
    }
  }

  if (dhalf) {
    *reinterpret_cast<float4*>(&S.outp[lane][0]) = make_float4(out[0], out[1], out[2], out[3]);
    *reinterpret_cast<float4*>(&S.outp[lane][4]) = make_float4(out[4], out[5], out[6], out[7]);
  }
  __syncthreads();   // b4: partials ready
  if (!dhalf) {
    float4 oa = *reinterpret_cast<const float4*>(&S.outp[lane][0]);
    float4 ob = *reinterpret_cast<const float4*>(&S.outp[lane][4]);
    out[0] += oa.x; out[1] += oa.y; out[2] += oa.z; out[3] += oa.w;
    out[4] += ob.x; out[5] += ob.y; out[6] += ob.z; out[7] += ob.w;
    // scramble store: scr[b][e*64 + n/64][(n%64)*8 + h], e = lane (16B/lane)
    uint32_t p0 = (uint32_t)f2b(out[0]) | ((uint32_t)f2b(out[1]) << 16);
    uint32_t p1 = (uint32_t)f2b(out[2]) | ((uint32_t)f2b(out[3]) << 16);
    uint32_t p2 = (uint32_t)f2b(out[4]) | ((uint32_t)f2b(out[5]) << 16);
    uint32_t p3 = (uint32_t)f2b(out[6]) | ((uint32_t)f2b(out[7]) << 16);
    uint4 pk; pk.x = p0; pk.y = p1; pk.z = p2; pk.w = p3;
    size_t doff = (size_t)b * 2097152 + ((size_t)lane * 64 + (size_t)(n >> 6)) * 512
                + (size_t)(n & 63) * 8;
    *reinterpret_cast<uint4*>(Sc + doff) = pk;
  }
}

// ---------------- launcher ----------------
extern "C" void kernel_launch(void* const* d_in, const int* in_sizes, int n_in,
                              void* d_out, int out_size, void* d_ws, size_t ws_size,
                              hipStream_t stream) {
  const float* x  = (const float*)d_in[0];
  const float* Wq = (const float*)d_in[1];
  const float* Wk = (const float*)d_in[2];
  const float* Wv = (const float*)d_in[3];
  const float* Pw = (const float*)d_in[5];
  const float* Pb = (const float*)d_in[6];
  float* out = (float*)d_out;

  const size_t MK = 16384ull * 512ull;
  u16* Xb   = (u16*)d_ws;          // 16.8 MB
  u16* QKVb = Xb + MK;             // 50.3 MB (fused [16384][1536])
  u16* Scr  = QKVb + 3 * MK;       // 16.8 MB
  u16* Wcat = Scr + MK;            // 1.5 MB ([1536][512] = Wq|Wk|Wv)
  u16* Pwb  = Wcat + 3 * 262144;   // 0.5 MB

  cvt_kernel<<<8192, 256, 0, stream>>>(x, Xb, 2097152);
  cvt4_kernel<<<1024, 256, 0, stream>>>(Wq, Wk, Wv, Pw,
                                        Wcat, Wcat + 262144, Wcat + 524288, Pwb);

  dim3 gq(12, 128);   // fused QKV: M=16384, N=1536, K=512
  gemm_bt<false><<<gq, 256, 0, stream>>>(Xb, Wcat, QKVb, nullptr, nullptr, 1536, 512);

  attn_pixel<<<8192, 256, 0, stream>>>(QKVb, Scr);

  dim3 gp(4, 128);
  gemm_bt<true><<<gp, 256, 0, stream>>>(Scr, Pwb, nullptr, out, Pb, 512, 512);
}